// Round 2
// baseline (536.694 us; speedup 1.0000x reference)
//
#include <hip/hip_runtime.h>

typedef unsigned int u32;
typedef unsigned char u8;
typedef unsigned short u16;
typedef __attribute__((ext_vector_type(4))) u32 u32x4;
typedef __attribute__((ext_vector_type(4))) int i32x4;
typedef __attribute__((ext_vector_type(4))) float f32x4;

#define DEV __device__ __forceinline__

// ---------------- workspace layout (bytes) ----------------
// spikes u8 [T=4][B=16][n=1024][c]; X2 f32 [t][b][c=256][n=1024]
static constexpr size_t XS_OFF  = 0;                            // 16 MB
static constexpr size_t QS_OFF  = XS_OFF  + (size_t)16777216;   // 16 MB (later aliased as YS)
static constexpr size_t KS_OFF  = QS_OFF  + (size_t)16777216;   // 16 MB
static constexpr size_t ATT_OFF = KS_OFF  + (size_t)16777216;   // 1 MB (uses 512KB)
static constexpr size_t X2_OFF  = ATT_OFF + (size_t)1048576;    // 64 MB
static constexpr size_t Z2_OFF  = X2_OFF  + (size_t)67108864;   // 64 MB
static constexpr size_t WQK_OFF = Z2_OFF  + (size_t)67108864;   // 512 KB (q||k digit planes)
static constexpr size_t WP_OFF  = WQK_OFF + (size_t)524288;     // 256 KB
static constexpr size_t W1_OFF  = WP_OFF  + (size_t)262144;     // 1 MB
static constexpr size_t W2_OFF  = W1_OFF  + (size_t)1048576;    // 1 MB
static constexpr size_t WS_NEED = W2_OFF  + (size_t)1048576;    // 188481536 B (== round-1 proven fit)
// aliases: YS = QS (QS dead after attn_k), Z = XS (XS dead after gemm<0>)

// ---------------- global_load_lds helper (width 16, linear dest) ----------------
DEV void gl_lds16(const void* gsrc, void* ldst){
  __builtin_amdgcn_global_load_lds(
      (const __attribute__((address_space(1))) unsigned int*)gsrc,
      (__attribute__((address_space(3))) unsigned int*)ldst, 16, 0, 0);
}

// ---------------- weight prep: f32 -> 4 signed-i8 digit planes in frag order ----------------
// w = Mhi*2^-15 + Mlo*2^-31 (exact to 0.5*2^-31); Mhi = d0*256+d1, Mlo = d2*256+d3
// frag (g,kt,ot): lane l, byte j  <->  w[o = ot*16+(l&15)][k = kt*64+(l>>4)*16+j]
__global__ __launch_bounds__(256) void prep_w(const float* __restrict__ S, signed char* __restrict__ D,
                                              int O, int Ck, int OTs, int otbase)
{
  int tid = blockIdx.x*256 + threadIdx.x;
  int tot = (O*Ck) >> 4;
  if (tid >= tot) return;
  int lane = tid & 63; int fo = tid >> 6;
  int OT = O >> 4; int KT = Ck >> 6;
  int kt = fo / OT; int ot = fo - kt*OT;
  int o = (ot<<4) + (lane&15);
  int c = (kt<<6) + ((lane>>4)<<4);
  const float* sp = S + (size_t)o*Ck + c;
  u8 dg[4][16];
#pragma unroll
  for (int j=0;j<16;j++){
    double w = (double)sp[j];
    int Mhi = (int)__double2ll_rn(w * 32768.0);
    double r = w - (double)Mhi * (1.0/32768.0);
    int Mlo = (int)__double2ll_rn(r * 2147483648.0);
    if (Mlo > 32639){ Mhi += 1; Mlo -= 65536; }       // keep digits in [-128,127]
    int d1 = (int)(signed char)(Mhi & 255); int d0 = (Mhi - d1) >> 8;
    int d3 = (int)(signed char)(Mlo & 255); int d2 = (Mlo - d3) >> 8;
    dg[0][j]=(u8)d0; dg[1][j]=(u8)d1; dg[2][j]=(u8)d2; dg[3][j]=(u8)d3;
  }
#pragma unroll
  for (int g=0; g<4; g++){
    signed char* dp = D + ((size_t)((g*KT + kt)*OTs + otbase + ot)<<10) + lane*16;
    *(u32x4*)dp = *(const u32x4*)dg[g];
  }
}

// ---------------- LIF on x -> xs spikes u8 [t][b][n][256] (exact f32 mirror) ----------------
__global__ __launch_bounds__(256,4) void lif_x(const float* __restrict__ X, u8* __restrict__ XSo)
{
  int tid = blockIdx.x*256 + threadIdx.x;          // 524288
  int n = tid & 1023; int oct = (tid>>10)&31; int b = tid>>15;
  int c0 = oct<<3;
  float mem[8];
#pragma unroll
  for (int i=0;i<8;i++) mem[i]=0.f;
#pragma unroll
  for (int t=0;t<4;t++){
    unsigned long long pk = 0ull;
    const float* xp = X + ((size_t)(((t*16+b)<<8) + c0)<<10) + n;
#pragma unroll
    for (int i=0;i<8;i++){
      float xv = xp[(size_t)i<<10];
      mem[i] = __fadd_rn(__fmul_rn(mem[i],0.5f), xv);
      bool s = mem[i] >= 1.0f;
      if (s) pk |= (1ull << (i*8));
      mem[i] = s? 0.f : mem[i];
    }
    *(unsigned long long*)(XSo + ((size_t)(((t*16+b)<<10) + n)<<8) + c0) = pk;
  }
}

// ---------------- attention: exact per-d EMA via history tables + LIF(0.5) ----------------
DEV u32 nib4(u32 u){ return ((u & 0x01010101u) * 0x01020408u) >> 24; }
DEV u32 pk16(u32x4 v){ return nib4(v[0]) | (nib4(v[1])<<4) | (nib4(v[2])<<8) | (nib4(v[3])<<12); }

__global__ __launch_bounds__(256,4) void attn_k(const u8* __restrict__ QS, u8* __restrict__ ATT,
                                                const float* __restrict__ alpha_p)
{
  const int tid = threadIdx.x; const int l = tid & 63; const int wv = tid>>6;
  int wid = blockIdx.x*4 + wv;                 // 0..2047
  int b = wid >> 7; int nc = wid & 127; int n0 = nc<<3;
  int nr = (l>>3)&7; int ch8 = l&7;
  const float a = alpha_p[0]; const float oma = __fsub_rn(1.0f, a);
  u32 mk[4];
#pragma unroll
  for (int t=0;t<4;t++){
    const u32x4* p = (const u32x4*)(QS + ((size_t)(((t*16+b)<<10) + n0 + nr) << 8));
    u32x4 v0 = p[ch8]; u32x4 v1 = p[8+ch8];
    u32 pa = pk16(v0), pb = pk16(v1);
    u32 qa = __shfl_xor(pa, 1); u32 qb = __shfl_xor(pb, 1);
    mk[t] = (l&1)? (qb | (pb<<16)) : (pa | (qa<<16));
  }
  float mt1[2], mt2[4], mt3[8];
#pragma unroll
  for (int q0=0;q0<2;q0++){
    mt1[q0] = __fadd_rn(__fmul_rn(a,(float)q0), __fmul_rn(oma,(float)q0));
#pragma unroll
    for (int q1=0;q1<2;q1++){
      mt2[q0+(q1<<1)] = __fadd_rn(__fmul_rn(a,mt1[q0]), __fmul_rn(oma,(float)q1));
#pragma unroll
      for (int q2=0;q2<2;q2++)
        mt3[q0+(q1<<1)+(q2<<2)] = __fadd_rn(__fmul_rn(a,mt2[q0+(q1<<1)]), __fmul_rn(oma,(float)q2));
    }
  }
  const int h = ((l&7)>>1) + ((l&1)<<2);
  const int n = n0 + nr;
  float mem = 0.f;
#pragma unroll
  for (int t=0;t<4;t++){
    u32 act = mk[0];
    if (t>=1) act |= mk[1];
    if (t>=2) act |= mk[2];
    if (t>=3) act |= mk[3];
    float qsum = 0.f;
    while (act){
      int d = __builtin_ctz(act); act &= act-1;
      int b0 = (mk[0]>>d)&1;
      float m;
      if (t==0) m = (float)b0;
      else if (t==1) m = mt1[b0];
      else if (t==2) m = mt2[b0 + (((mk[1]>>d)&1)<<1)];
      else m = mt3[b0 + (((mk[1]>>d)&1)<<1) + (((mk[2]>>d)&1)<<2)];
      float qd = (float)((mk[t]>>d)&1);
      qsum = __fadd_rn(qsum, __fadd_rn(m, qd));   // ascending d; zero terms exact no-ops
    }
    mem = __fadd_rn(__fmul_rn(mem, 0.5f), qsum);
    bool s = mem >= 0.5f;
    ATT[((size_t)(((t*16+b)<<3) + h)<<10) + n] = s? (u8)1 : (u8)0;
    mem = s? 0.f : mem;
  }
}

// ---------------- y = k-spikes AND attn (exact {0,1}) ----------------
__global__ __launch_bounds__(256) void mask_k(const u8* __restrict__ KS,
                                              const u8* __restrict__ ATT, u8* __restrict__ YS)
{
  int tid = blockIdx.x*256 + threadIdx.x;        // 1048576
  int c4 = tid & 15; int n = (tid>>4) & 1023; int tb = tid >> 14;
  int h = c4 >> 1;
  u8 m = ATT[((size_t)((tb<<3) + h)<<10) + n];
  size_t row = ((size_t)((tb<<10)+n))<<8;
  u32x4 v = *(const u32x4*)(KS + row + c4*16);
  if (!m) v = (u32x4){0,0,0,0};
  *(u32x4*)(YS + row + c4*16) = v;
}

// ---------------- exact spike GEMM via 4-digit i8 MFMA ----------------
// out[n][o] = sum_c spike[n][c] * w[o][c]  (exact integer digit sums, double-combined)
// block: n64 x o32 x t4; wave wv: rows wv*16..+15, stages t=wv A-plane
template<int MODE>
__global__ __launch_bounds__(256,2) void gemm_i8(
    const u8* __restrict__ A, const signed char* __restrict__ W,
    const float* __restrict__ G1, const float* __restrict__ B1,
    const float* __restrict__ G2, const float* __restrict__ B2,
    const float* __restrict__ BIAS, const float* __restrict__ XRES,
    float* __restrict__ FOUT, u8* __restrict__ SOUT, u8* __restrict__ SOUT2)
{
  constexpr int KC   = (MODE==3)? 1024 : 256;
  constexpr int KT   = KC >> 6;
  constexpr int OTOT = (MODE==0)? 32 : (MODE==2)? 64 : 16;
  constexpr int NOB  = OTOT >> 1;
  constexpr int NWG  = NOB*256;

  const int tid = threadIdx.x;
  const int bid = blockIdx.x;
  const int wid = (bid & 7)*(NWG>>3) + (bid>>3);     // bijective XCD swizzle (NWG%8==0)
  const int ob = wid % NOB; const int rr = wid / NOB;
  const int nb = rr & 15; const int b = rr >> 4;

  __shared__ __align__(16) u8 Al[16384];   // [t4][chunk4][n64][16]
  __shared__ __align__(16) u8 Bl[8192];    // [g4][os2][1024] lane-major frags

  const int lane = tid & 63, wv = tid >> 6;

  // A staging: wave wv stages its t=wv plane; lane = n-row
  const u8* aRowG = A + (size_t)(((wv*16 + b)<<10) + nb*64 + lane)*KC;
  u8* aDst = Al + (wv<<2)*1024;

  i32x4 acc[4][2][4];                      // [digit g][os][t]
#pragma unroll
  for (int g=0;g<4;g++)
#pragma unroll
    for (int os=0;os<2;os++)
#pragma unroll
      for (int t=0;t<4;t++) acc[g][os][t] = (i32x4){0,0,0,0};

  for (int kt=0; kt<KT; ++kt){
    __syncthreads();                       // prev-iter LDS reads done
    const u8* as = aRowG + kt*64;
#pragma unroll
    for (int c=0;c<4;c++) gl_lds16(as + c*16, aDst + c*1024);
#pragma unroll
    for (int q2=0;q2<2;q2++){
      int fi = wv*2 + q2;                  // g = fi>>1, os = fi&1
      const signed char* bs = W + ((size_t)(((fi>>1)*KT + kt)*OTOT + ob*2 + (fi&1))<<10) + lane*16;
      gl_lds16(bs, Bl + (fi<<10));
    }
    __syncthreads();                       // staging visible (vmcnt(0) auto before barrier)

    i32x4 af[4];
#pragma unroll
    for (int t=0;t<4;t++)
      af[t] = *(const i32x4*)(Al + (((t<<2) + (lane>>4))*64 + (wv<<4) + (lane&15))*16);
#pragma unroll
    for (int g=0; g<4; ++g)
#pragma unroll
      for (int os=0; os<2; ++os){
        i32x4 bf = *(const i32x4*)(Bl + (((g<<1)+os)<<10) + lane*16);
#pragma unroll
        for (int t=0;t<4;t++)
          acc[g][os][t] = __builtin_amdgcn_mfma_i32_16x16x64_i8(af[t], bf, acc[g][os][t], 0,0,0);
      }
  }

  // ---------------- digit combine (exact) + bn + LIF epilogues ----------------
  const int g4 = lane >> 4;
  const int nq = nb*64 + (wv<<4) + (g4<<2);

  float pre[2][4][4];                      // [os][t][jj]
#pragma unroll
  for (int os=0;os<2;++os)
#pragma unroll
    for (int t=0;t<4;++t)
#pragma unroll
      for (int jj=0;jj<4;++jj){
        int shi = (acc[0][os][t][jj] << 8) + acc[1][os][t][jj];
        int slo = (acc[2][os][t][jj] << 8) + acc[3][os][t][jj];
        pre[os][t][jj] = (float)((double)shi * 0x1p-15 + (double)slo * 0x1p-31);
      }

  if constexpr (MODE==0){
#pragma unroll
    for (int os=0; os<2; ++os){
      const int o = (ob<<5) + (os<<4) + (lane&15);   // 0..511 over q||k
      const int matk = o>>8; const int om = o & 255;
      const float gg = (matk? G2 : G1)[om];
      const float bb = (matk? B2 : B1)[om];
      u8* sp = matk? SOUT2 : SOUT;
#pragma unroll
      for (int jj=0;jj<4;jj++){
        float mem = 0.f; const int n = nq + jj;
#pragma unroll
        for (int t=0;t<4;t++){
          float v = __fadd_rn(__fmul_rn(pre[os][t][jj], gg), bb);
          mem = __fadd_rn(__fmul_rn(mem, 0.5f), v);
          const bool s = mem >= 1.0f;
          sp[(size_t)(((t*16 + b)<<10) + n)*256 + om] = s? (u8)1 : (u8)0;
          mem = s? 0.f : mem;
        }
      }
    }
  } else if constexpr (MODE==1){
#pragma unroll
    for (int os=0; os<2; ++os){
      const int o = (ob<<5) + (os<<4) + (lane&15);   // 0..255
      const float pg = G1[o], pb2v = B1[o], pbv = BIAS[o];
      float xv[4][4];
#pragma unroll
      for (int t=0;t<4;t++){
        const size_t base = ((size_t)(((t*16 + b)<<8) + o)<<10) + nq;
        const f32x4 xq = *(const f32x4*)(XRES + base);
        f32x4 ov;
#pragma unroll
        for (int jj=0;jj<4;jj++){
          float y2 = __fadd_rn(__fmul_rn(__fadd_rn(pre[os][t][jj], pbv), pg), pb2v);
          float xx = __fadd_rn(xq[jj], y2);
          xv[t][jj] = xx; ov[jj] = xx;
        }
        *(f32x4*)(FOUT + base) = ov;                 // x2 = x + y
      }
#pragma unroll
      for (int jj=0;jj<4;jj++){
        float mem = 0.f; const int n = nq + jj;
#pragma unroll
        for (int t=0;t<4;t++){
          mem = __fadd_rn(__fmul_rn(mem, 0.5f), xv[t][jj]);
          const bool s = mem >= 1.0f;
          SOUT[(size_t)(((t*16 + b)<<10) + n)*256 + o] = s? (u8)1 : (u8)0;   // z spikes
          mem = s? 0.f : mem;
        }
      }
    }
  } else if constexpr (MODE==2){
#pragma unroll
    for (int os=0; os<2; ++os){
      const int o = (ob<<5) + (os<<4) + (lane&15);   // 0..1023
      const float gg = G1[o], bb = B1[o], bv = BIAS[o];
#pragma unroll
      for (int jj=0;jj<4;jj++){
        float mem = 0.f; const int n = nq + jj;
#pragma unroll
        for (int t=0;t<4;t++){
          float v = __fadd_rn(__fmul_rn(__fadd_rn(pre[os][t][jj], bv), gg), bb);
          mem = __fadd_rn(__fmul_rn(mem, 0.5f), v);
          const bool s = mem >= 1.0f;
          SOUT[(size_t)(((t*16 + b)<<10) + n)*1024 + o] = s? (u8)1 : (u8)0;  // z2 spikes
          mem = s? 0.f : mem;
        }
      }
    }
  } else {
#pragma unroll
    for (int os=0; os<2; ++os){
      const int o = (ob<<5) + (os<<4) + (lane&15);   // 0..255
      const float gg = G1[o], bb = B1[o], bv = BIAS[o];
#pragma unroll
      for (int t=0;t<4;t++){
        const size_t base = ((size_t)(((t*16 + b)<<8) + o)<<10) + nq;
        const f32x4 xq = *(const f32x4*)(XRES + base);
        f32x4 ov;
#pragma unroll
        for (int jj=0;jj<4;jj++){
          float v = __fadd_rn(__fmul_rn(__fadd_rn(pre[os][t][jj], bv), gg), bb);
          ov[jj] = __fadd_rn(xq[jj], v);
        }
        *(f32x4*)(FOUT + base) = ov;                 // final output
      }
    }
  }
}

// ---------------- host launcher ----------------
extern "C" void kernel_launch(void* const* d_in, const int* in_sizes, int n_in,
                              void* d_out, int out_size, void* d_ws, size_t ws_size,
                              hipStream_t stream)
{
  (void)in_sizes; (void)n_in; (void)out_size;
  if (ws_size < WS_NEED) return;

  const float* x      = (const float*)d_in[0];
  const float* q_w    = (const float*)d_in[1];
  const float* q_g    = (const float*)d_in[2];
  const float* q_b    = (const float*)d_in[3];
  const float* k_w    = (const float*)d_in[4];
  const float* k_g    = (const float*)d_in[5];
  const float* k_b    = (const float*)d_in[6];
  const float* p_w    = (const float*)d_in[7];
  const float* p_bias = (const float*)d_in[8];
  const float* p_g    = (const float*)d_in[9];
  const float* p_b2   = (const float*)d_in[10];
  const float* alpha  = (const float*)d_in[11];
  const float* w1     = (const float*)d_in[12];
  const float* b1     = (const float*)d_in[13];
  const float* bn1g   = (const float*)d_in[14];
  const float* bn1b   = (const float*)d_in[15];
  const float* w2     = (const float*)d_in[16];
  const float* b2     = (const float*)d_in[17];
  const float* bn2g   = (const float*)d_in[18];
  const float* bn2b   = (const float*)d_in[19];

  u8* ws  = (u8*)d_ws;
  u8* XS  = ws + XS_OFF;
  u8* QS  = ws + QS_OFF;
  u8* KS  = ws + KS_OFF;
  u8* ATT = ws + ATT_OFF;
  float* X2 = (float*)(ws + X2_OFF);
  u8* Z2  = ws + Z2_OFF;
  u8* YS  = QS;                        // alias: QS dead after attn_k
  u8* Z   = XS;                        // alias: XS dead after gemm<0>
  signed char* WQK = (signed char*)(ws + WQK_OFF);
  signed char* WPp = (signed char*)(ws + WP_OFF);
  signed char* W1p = (signed char*)(ws + W1_OFF);
  signed char* W2p = (signed char*)(ws + W2_OFF);

  prep_w<<<16, 256, 0, stream>>>(q_w, WQK, 256, 256, 32, 0);
  prep_w<<<16, 256, 0, stream>>>(k_w, WQK, 256, 256, 32, 16);
  prep_w<<<16, 256, 0, stream>>>(p_w, WPp, 256, 256, 16, 0);
  prep_w<<<64, 256, 0, stream>>>(w1,  W1p, 1024, 256, 64, 0);
  prep_w<<<64, 256, 0, stream>>>(w2,  W2p, 256, 1024, 16, 0);

  lif_x<<<2048, 256, 0, stream>>>(x, XS);

  // QK fused (o-space = q||k, 512): q,k spikes
  gemm_i8<0><<<4096, 256, 0, stream>>>(XS, WQK, q_g, q_b, k_g, k_b,
                                       nullptr, nullptr, nullptr, QS, KS);

  attn_k<<<512, 256, 0, stream>>>(QS, ATT, alpha);
  mask_k<<<4096, 256, 0, stream>>>(KS, ATT, YS);

  // proj: x2 = x + bn(y@proj_w + bias), z = lif(x2)
  gemm_i8<1><<<2048, 256, 0, stream>>>(YS, WPp, p_g, p_b2, nullptr, nullptr,
                                       p_bias, x, X2, Z, nullptr);

  // mlp1: z2 = lif(bn1(z@w1^T + b1))
  gemm_i8<2><<<8192, 256, 0, stream>>>(Z, W1p, bn1g, bn1b, nullptr, nullptr,
                                       b1, nullptr, nullptr, Z2, nullptr);

  // mlp2: out = x2 + bn2(z2@w2^T + b2)
  gemm_i8<3><<<2048, 256, 0, stream>>>(Z2, W2p, bn2g, bn2b, nullptr, nullptr,
                                       b2, X2, (float*)d_out, nullptr, nullptr);
}

// Round 3
// 517.682 us; speedup vs baseline: 1.0367x; 1.0367x over previous
//
#include <hip/hip_runtime.h>

typedef unsigned int u32;
typedef unsigned char u8;
typedef unsigned short u16;
typedef __attribute__((ext_vector_type(4))) u32 u32x4;
typedef __attribute__((ext_vector_type(4))) int i32x4;
typedef __attribute__((ext_vector_type(4))) float f32x4;

#define DEV __device__ __forceinline__

// ---------------- workspace layout (bytes) ----------------
static constexpr size_t XS_OFF  = 0;                            // 16 MB
static constexpr size_t QS_OFF  = XS_OFF  + (size_t)16777216;   // 16 MB (later aliased as YS)
static constexpr size_t KS_OFF  = QS_OFF  + (size_t)16777216;   // 16 MB
static constexpr size_t ATT_OFF = KS_OFF  + (size_t)16777216;   // 1 MB (uses 512KB)
static constexpr size_t X2_OFF  = ATT_OFF + (size_t)1048576;    // 64 MB
static constexpr size_t Z2_OFF  = X2_OFF  + (size_t)67108864;   // 64 MB
static constexpr size_t WQK_OFF = Z2_OFF  + (size_t)67108864;   // 512 KB (q||k digit planes)
static constexpr size_t WP_OFF  = WQK_OFF + (size_t)524288;     // 256 KB
static constexpr size_t W1_OFF  = WP_OFF  + (size_t)262144;     // 1 MB
static constexpr size_t W2_OFF  = W1_OFF  + (size_t)1048576;    // 1 MB
static constexpr size_t WS_NEED = W2_OFF  + (size_t)1048576;
// aliases: YS = QS (QS dead after attn_k), Z = XS (XS dead after gemm<0>)

// ---------------- global_load_lds helper (width 16, linear dest) ----------------
DEV void gl_lds16(const void* gsrc, void* ldst){
  __builtin_amdgcn_global_load_lds(
      (const __attribute__((address_space(1))) unsigned int*)gsrc,
      (__attribute__((address_space(3))) unsigned int*)ldst, 16, 0, 0);
}

// ---------------- merged weight prep: f32 -> 4 signed-i8 digit planes, frag order ----
// w = Mhi*2^-15 + Mlo*2^-31 (|err| <= 0.5*2^-31); Mhi = d0*256+d1, Mlo = d2*256+d3
// frag (g,kt,ot): lane l, byte j  <->  w[o = ot*16+(l&15)][k = kt*64+(l>>4)*16+j]
__global__ __launch_bounds__(256) void prep_all(
    const float* __restrict__ q_w, const float* __restrict__ k_w,
    const float* __restrict__ p_w, const float* __restrict__ w1,
    const float* __restrict__ w2,
    signed char* __restrict__ WQK, signed char* __restrict__ WP,
    signed char* __restrict__ W1p, signed char* __restrict__ W2p)
{
  const int bb = blockIdx.x;
  const float* S; signed char* D; int O, Ck, OTs, otbase, base;
  if      (bb < 16) { S=q_w; D=WQK; O=256;  Ck=256;  OTs=32; otbase=0;  base=0;   }
  else if (bb < 32) { S=k_w; D=WQK; O=256;  Ck=256;  OTs=32; otbase=16; base=16;  }
  else if (bb < 48) { S=p_w; D=WP;  O=256;  Ck=256;  OTs=16; otbase=0;  base=32;  }
  else if (bb <112) { S=w1;  D=W1p; O=1024; Ck=256;  OTs=64; otbase=0;  base=48;  }
  else              { S=w2;  D=W2p; O=256;  Ck=1024; OTs=16; otbase=0;  base=112; }
  int tid = (bb - base)*256 + threadIdx.x;
  int lane = tid & 63; int fo = tid >> 6;
  int OT = O >> 4; int KT = Ck >> 6;
  int kt = fo / OT; int ot = fo - kt*OT;
  int o = (ot<<4) + (lane&15);
  int c = (kt<<6) + ((lane>>4)<<4);
  const float* sp = S + (size_t)o*Ck + c;
  u8 dg[4][16];
#pragma unroll
  for (int j=0;j<16;j++){
    double w = (double)sp[j];
    int Mhi = (int)__double2ll_rn(w * 32768.0);
    double r = w - (double)Mhi * (1.0/32768.0);
    int Mlo = (int)__double2ll_rn(r * 2147483648.0);
    if (Mlo > 32639){ Mhi += 1; Mlo -= 65536; }
    int d1 = (int)(signed char)(Mhi & 255); int d0 = (Mhi - d1) >> 8;
    int d3 = (int)(signed char)(Mlo & 255); int d2 = (Mlo - d3) >> 8;
    dg[0][j]=(u8)d0; dg[1][j]=(u8)d1; dg[2][j]=(u8)d2; dg[3][j]=(u8)d3;
  }
#pragma unroll
  for (int g=0; g<4; g++){
    signed char* dp = D + ((size_t)((g*KT + kt)*OTs + otbase + ot)<<10) + lane*16;
    *(u32x4*)dp = *(const u32x4*)dg[g];
  }
}

// ---------------- LIF on x -> xs spikes u8 [t][b][n][256] (exact f32 mirror) --------
__global__ __launch_bounds__(256,4) void lif_x(const float* __restrict__ X, u8* __restrict__ XSo)
{
  int tid = blockIdx.x*256 + threadIdx.x;          // 524288
  int n = tid & 1023; int oct = (tid>>10)&31; int b = tid>>15;
  int c0 = oct<<3;
  float mem[8];
#pragma unroll
  for (int i=0;i<8;i++) mem[i]=0.f;
#pragma unroll
  for (int t=0;t<4;t++){
    unsigned long long pk = 0ull;
    const float* xp = X + ((size_t)(((t*16+b)<<8) + c0)<<10) + n;
#pragma unroll
    for (int i=0;i<8;i++){
      float xv = xp[(size_t)i<<10];
      mem[i] = __fadd_rn(__fmul_rn(mem[i],0.5f), xv);
      bool s = mem[i] >= 1.0f;
      if (s) pk |= (1ull << (i*8));
      mem[i] = s? 0.f : mem[i];
    }
    *(unsigned long long*)(XSo + ((size_t)(((t*16+b)<<10) + n)<<8) + c0) = pk;
  }
}

// ---------------- attention: exact per-d EMA via history tables + LIF(0.5) ----------
DEV u32 nib4(u32 u){ return ((u & 0x01010101u) * 0x01020408u) >> 24; }
DEV u32 pk16(u32x4 v){ return nib4(v[0]) | (nib4(v[1])<<4) | (nib4(v[2])<<8) | (nib4(v[3])<<12); }

__global__ __launch_bounds__(256,4) void attn_k(const u8* __restrict__ QS, u8* __restrict__ ATT,
                                                const float* __restrict__ alpha_p)
{
  const int tid = threadIdx.x; const int l = tid & 63; const int wv = tid>>6;
  int wid = blockIdx.x*4 + wv;                 // 0..2047
  int b = wid >> 7; int nc = wid & 127; int n0 = nc<<3;
  int nr = (l>>3)&7; int ch8 = l&7;
  const float a = alpha_p[0]; const float oma = __fsub_rn(1.0f, a);
  u32 mk[4];
#pragma unroll
  for (int t=0;t<4;t++){
    const u32x4* p = (const u32x4*)(QS + ((size_t)(((t*16+b)<<10) + n0 + nr) << 8));
    u32x4 v0 = p[ch8]; u32x4 v1 = p[8+ch8];
    u32 pa = pk16(v0), pb = pk16(v1);
    u32 qa = __shfl_xor(pa, 1); u32 qb = __shfl_xor(pb, 1);
    mk[t] = (l&1)? (qb | (pb<<16)) : (pa | (qa<<16));
  }
  float mt1[2], mt2[4], mt3[8];
#pragma unroll
  for (int q0=0;q0<2;q0++){
    mt1[q0] = __fadd_rn(__fmul_rn(a,(float)q0), __fmul_rn(oma,(float)q0));
#pragma unroll
    for (int q1=0;q1<2;q1++){
      mt2[q0+(q1<<1)] = __fadd_rn(__fmul_rn(a,mt1[q0]), __fmul_rn(oma,(float)q1));
#pragma unroll
      for (int q2=0;q2<2;q2++)
        mt3[q0+(q1<<1)+(q2<<2)] = __fadd_rn(__fmul_rn(a,mt2[q0+(q1<<1)]), __fmul_rn(oma,(float)q2));
    }
  }
  const int h = ((l&7)>>1) + ((l&1)<<2);
  const int n = n0 + nr;
  float mem = 0.f;
#pragma unroll
  for (int t=0;t<4;t++){
    u32 act = mk[0];
    if (t>=1) act |= mk[1];
    if (t>=2) act |= mk[2];
    if (t>=3) act |= mk[3];
    float qsum = 0.f;
    while (act){
      int d = __builtin_ctz(act); act &= act-1;
      int b0 = (mk[0]>>d)&1;
      float m;
      if (t==0) m = (float)b0;
      else if (t==1) m = mt1[b0];
      else if (t==2) m = mt2[b0 + (((mk[1]>>d)&1)<<1)];
      else m = mt3[b0 + (((mk[1]>>d)&1)<<1) + (((mk[2]>>d)&1)<<2)];
      float qd = (float)((mk[t]>>d)&1);
      qsum = __fadd_rn(qsum, __fadd_rn(m, qd));   // ascending d; zero terms exact no-ops
    }
    mem = __fadd_rn(__fmul_rn(mem, 0.5f), qsum);
    bool s = mem >= 0.5f;
    ATT[((size_t)(((t*16+b)<<3) + h)<<10) + n] = s? (u8)1 : (u8)0;
    mem = s? 0.f : mem;
  }
}

// ---------------- y = k-spikes AND attn (exact {0,1}) ----------------
__global__ __launch_bounds__(256) void mask_k(const u8* __restrict__ KS,
                                              const u8* __restrict__ ATT, u8* __restrict__ YS)
{
  int tid = blockIdx.x*256 + threadIdx.x;        // 1048576
  int c4 = tid & 15; int n = (tid>>4) & 1023; int tb = tid >> 14;
  int h = c4 >> 1;
  u8 m = ATT[((size_t)((tb<<3) + h)<<10) + n];
  size_t row = ((size_t)((tb<<10)+n))<<8;
  u32x4 v = *(const u32x4*)(KS + row + c4*16);
  if (!m) v = (u32x4){0,0,0,0};
  *(u32x4*)(YS + row + c4*16) = v;
}

// ---------------- exact spike GEMM via 4-digit i8 MFMA, pipelined ----------------
// out[n][o] = sum_c spike[n][c] * w[o][c]  (exact integer digit sums, double-combined)
// block: n64 x o32 x t4; double-buffered A; B staged up-front for KT=4 modes.
template<int MODE>
__global__ __launch_bounds__(256,2) void gemm_i8(
    const u8* __restrict__ A, const signed char* __restrict__ W,
    const float* __restrict__ G1, const float* __restrict__ B1,
    const float* __restrict__ G2, const float* __restrict__ B2,
    const float* __restrict__ BIAS, const float* __restrict__ XRES,
    float* __restrict__ FOUT, u8* __restrict__ SOUT, u8* __restrict__ SOUT2)
{
  constexpr int KC   = (MODE==3)? 1024 : 256;
  constexpr int KT   = KC >> 6;
  constexpr int OTOT = (MODE==0)? 32 : (MODE==2)? 64 : 16;
  constexpr int NOB  = OTOT >> 1;
  constexpr int NWG  = NOB*256;
  constexpr bool BUP = (MODE != 3);               // B staged up-front

  const int tid = threadIdx.x;
  const int bid = blockIdx.x;
  const int wid = (bid & 7)*(NWG>>3) + (bid>>3);  // bijective XCD swizzle (NWG%8==0)
  const int ob = wid % NOB; const int rr = wid / NOB;
  const int nb = rr & 15; const int b = rr >> 4;

  __shared__ __align__(16) u8 Al[2][16384];       // [t4][chunk4][row64][16]
  __shared__ __align__(16) u8 Bl[BUP ? 32768 : 16384];

  const int lane = tid & 63, wv = tid >> 6;

  // A staging: wave wv stages its t=wv plane; lane = n-row
  const u8* aRowG = A + (size_t)(((wv*16 + b)<<10) + nb*64 + lane)*KC;

  auto stageA = [&](int kt, int p){
    const u8* as = aRowG + kt*64;
    u8* ad = Al[p] + (wv<<2)*1024;
#pragma unroll
    for (int c=0;c<4;c++) gl_lds16(as + c*16, ad + c*1024);
  };
  auto stageB3 = [&](int kt, int p){              // MODE3 per-phase B (2 frags/wave)
#pragma unroll
    for (int q2=0;q2<2;q2++){
      int fi = wv*2 + q2;
      const signed char* bs = W + ((size_t)(((fi>>1)*KT + kt)*OTOT + ob*2 + (fi&1))<<10) + lane*16;
      gl_lds16(bs, Bl + p*8192 + (fi<<10));
    }
  };

  i32x4 acc[4][2][4];                             // [digit g][os][t]
#pragma unroll
  for (int g=0;g<4;g++)
#pragma unroll
    for (int os=0;os<2;os++)
#pragma unroll
      for (int t=0;t<4;t++) acc[g][os][t] = (i32x4){0,0,0,0};

  if constexpr (BUP){
    // 32 frags [g][os][kt]; thread covers f = wv + j*4
#pragma unroll
    for (int j=0;j<8;j++){
      int f = wv + j*4;                           // 0..31; f = (g*2+os)*4 + kt
      int g = f >> 3; int os = (f>>2)&1; int kt = f&3;
      const signed char* bs = W + ((size_t)((g*KT + kt)*OTOT + ob*2 + os)<<10) + lane*16;
      gl_lds16(bs, Bl + (f<<10));
    }
  }
  stageA(0, 0);
  if constexpr (!BUP) stageB3(0, 0);

  auto compute = [&](int p, int kt){
    i32x4 af[4];
#pragma unroll
    for (int t=0;t<4;t++)
      af[t] = *(const i32x4*)(Al[p] + (((t<<2)+(lane>>4))<<10) + (((wv<<4)+(lane&15))<<4));
    __builtin_amdgcn_s_setprio(1);
#pragma unroll
    for (int g=0; g<4; ++g)
#pragma unroll
      for (int os=0; os<2; ++os){
        const u8* bp;
        if constexpr (BUP) bp = Bl + (((((g<<1)+os)<<2) | kt)<<10);
        else               bp = Bl + p*8192 + ((((g<<1)+os))<<10);
        i32x4 bf = *(const i32x4*)(bp + (lane<<4));
#pragma unroll
        for (int t=0;t<4;t++)
          acc[g][os][t] = __builtin_amdgcn_mfma_i32_16x16x64_i8(af[t], bf, acc[g][os][t], 0,0,0);
      }
    __builtin_amdgcn_s_setprio(0);
  };

#pragma unroll
  for (int kt=0; kt<KT; ++kt){
    const int p = kt & 1;
    if (kt+1 < KT){
      stageA(kt+1, p^1);
      if constexpr (!BUP) stageB3(kt+1, p^1);
      if constexpr (BUP) asm volatile("s_waitcnt vmcnt(4)" ::: "memory");
      else               asm volatile("s_waitcnt vmcnt(6)" ::: "memory");
    } else {
      asm volatile("s_waitcnt vmcnt(0)" ::: "memory");
    }
    __builtin_amdgcn_s_barrier();                 // kt's staging visible everywhere
    compute(p, kt);
    asm volatile("s_waitcnt lgkmcnt(0)" ::: "memory");
    __builtin_amdgcn_s_barrier();                 // LDS reads done before buf reuse
  }

  // ---------------- digit combine (exact) + bn + LIF epilogues ----------------
  const int g4 = lane >> 4;
  const int nq = nb*64 + (wv<<4) + (g4<<2);

  float pre[2][4][4];                             // [os][t][jj]
#pragma unroll
  for (int os=0;os<2;++os)
#pragma unroll
    for (int t=0;t<4;++t)
#pragma unroll
      for (int jj=0;jj<4;++jj){
        int shi = (acc[0][os][t][jj] << 8) + acc[1][os][t][jj];
        int slo = (acc[2][os][t][jj] << 8) + acc[3][os][t][jj];
        pre[os][t][jj] = (float)((double)shi * 0x1p-15 + (double)slo * 0x1p-31);
      }

  if constexpr (MODE==0){
#pragma unroll
    for (int os=0; os<2; ++os){
      const int o = (ob<<5) + (os<<4) + (lane&15);   // 0..511 over q||k
      const int matk = o>>8; const int om = o & 255;
      const float gg = (matk? G2 : G1)[om];
      const float bb = (matk? B2 : B1)[om];
      u8* sp = matk? SOUT2 : SOUT;
#pragma unroll
      for (int jj=0;jj<4;jj++){
        float mem = 0.f; const int n = nq + jj;
#pragma unroll
        for (int t=0;t<4;t++){
          float v = __fadd_rn(__fmul_rn(pre[os][t][jj], gg), bb);
          mem = __fadd_rn(__fmul_rn(mem, 0.5f), v);
          const bool s = mem >= 1.0f;
          sp[(size_t)(((t*16 + b)<<10) + n)*256 + om] = s? (u8)1 : (u8)0;
          mem = s? 0.f : mem;
        }
      }
    }
  } else if constexpr (MODE==1){
#pragma unroll
    for (int os=0; os<2; ++os){
      const int o = (ob<<5) + (os<<4) + (lane&15);   // 0..255
      const float pg = G1[o], pb2v = B1[o], pbv = BIAS[o];
      float xv[4][4];
#pragma unroll
      for (int t=0;t<4;t++){
        const size_t base = ((size_t)(((t*16 + b)<<8) + o)<<10) + nq;
        const f32x4 xq = *(const f32x4*)(XRES + base);
        f32x4 ov;
#pragma unroll
        for (int jj=0;jj<4;jj++){
          float y2 = __fadd_rn(__fmul_rn(__fadd_rn(pre[os][t][jj], pbv), pg), pb2v);
          float xx = __fadd_rn(xq[jj], y2);
          xv[t][jj] = xx; ov[jj] = xx;
        }
        *(f32x4*)(FOUT + base) = ov;                 // x2 = x + y
      }
#pragma unroll
      for (int jj=0;jj<4;jj++){
        float mem = 0.f; const int n = nq + jj;
#pragma unroll
        for (int t=0;t<4;t++){
          mem = __fadd_rn(__fmul_rn(mem, 0.5f), xv[t][jj]);
          const bool s = mem >= 1.0f;
          SOUT[(size_t)(((t*16 + b)<<10) + n)*256 + o] = s? (u8)1 : (u8)0;   // z spikes
          mem = s? 0.f : mem;
        }
      }
    }
  } else if constexpr (MODE==2){
#pragma unroll
    for (int os=0; os<2; ++os){
      const int o = (ob<<5) + (os<<4) + (lane&15);   // 0..1023
      const float gg = G1[o], bb = B1[o], bv = BIAS[o];
#pragma unroll
      for (int jj=0;jj<4;jj++){
        float mem = 0.f; const int n = nq + jj;
#pragma unroll
        for (int t=0;t<4;t++){
          float v = __fadd_rn(__fmul_rn(__fadd_rn(pre[os][t][jj], bv), gg), bb);
          mem = __fadd_rn(__fmul_rn(mem, 0.5f), v);
          const bool s = mem >= 1.0f;
          SOUT[(size_t)(((t*16 + b)<<10) + n)*1024 + o] = s? (u8)1 : (u8)0;  // z2 spikes
          mem = s? 0.f : mem;
        }
      }
    }
  } else {
#pragma unroll
    for (int os=0; os<2; ++os){
      const int o = (ob<<5) + (os<<4) + (lane&15);   // 0..255
      const float gg = G1[o], bb = B1[o], bv = BIAS[o];
#pragma unroll
      for (int t=0;t<4;t++){
        const size_t base = ((size_t)(((t*16 + b)<<8) + o)<<10) + nq;
        const f32x4 xq = *(const f32x4*)(XRES + base);
        f32x4 ov;
#pragma unroll
        for (int jj=0;jj<4;jj++){
          float v = __fadd_rn(__fmul_rn(__fadd_rn(pre[os][t][jj], bv), gg), bb);
          ov[jj] = __fadd_rn(xq[jj], v);
        }
        *(f32x4*)(FOUT + base) = ov;                 // final output
      }
    }
  }
}

// ---------------- host launcher ----------------
extern "C" void kernel_launch(void* const* d_in, const int* in_sizes, int n_in,
                              void* d_out, int out_size, void* d_ws, size_t ws_size,
                              hipStream_t stream)
{
  (void)in_sizes; (void)n_in; (void)out_size;
  if (ws_size < WS_NEED) return;

  const float* x      = (const float*)d_in[0];
  const float* q_w    = (const float*)d_in[1];
  const float* q_g    = (const float*)d_in[2];
  const float* q_b    = (const float*)d_in[3];
  const float* k_w    = (const float*)d_in[4];
  const float* k_g    = (const float*)d_in[5];
  const float* k_b    = (const float*)d_in[6];
  const float* p_w    = (const float*)d_in[7];
  const float* p_bias = (const float*)d_in[8];
  const float* p_g    = (const float*)d_in[9];
  const float* p_b2   = (const float*)d_in[10];
  const float* alpha  = (const float*)d_in[11];
  const float* w1     = (const float*)d_in[12];
  const float* b1     = (const float*)d_in[13];
  const float* bn1g   = (const float*)d_in[14];
  const float* bn1b   = (const float*)d_in[15];
  const float* w2     = (const float*)d_in[16];
  const float* b2     = (const float*)d_in[17];
  const float* bn2g   = (const float*)d_in[18];
  const float* bn2b   = (const float*)d_in[19];

  u8* ws  = (u8*)d_ws;
  u8* XS  = ws + XS_OFF;
  u8* QS  = ws + QS_OFF;
  u8* KS  = ws + KS_OFF;
  u8* ATT = ws + ATT_OFF;
  float* X2 = (float*)(ws + X2_OFF);
  u8* Z2  = ws + Z2_OFF;
  u8* YS  = QS;                        // alias: QS dead after attn_k
  u8* Z   = XS;                        // alias: XS dead after gemm<0>
  signed char* WQK = (signed char*)(ws + WQK_OFF);
  signed char* WPp = (signed char*)(ws + WP_OFF);
  signed char* W1p = (signed char*)(ws + W1_OFF);
  signed char* W2p = (signed char*)(ws + W2_OFF);

  prep_all<<<176, 256, 0, stream>>>(q_w, k_w, p_w, w1, w2, WQK, WPp, W1p, W2p);

  lif_x<<<2048, 256, 0, stream>>>(x, XS);

  // QK fused (o-space = q||k, 512): q,k spikes
  gemm_i8<0><<<4096, 256, 0, stream>>>(XS, WQK, q_g, q_b, k_g, k_b,
                                       nullptr, nullptr, nullptr, QS, KS);

  attn_k<<<512, 256, 0, stream>>>(QS, ATT, alpha);
  mask_k<<<4096, 256, 0, stream>>>(KS, ATT, YS);

  // proj: x2 = x + bn(y@proj_w + bias), z = lif(x2)
  gemm_i8<1><<<2048, 256, 0, stream>>>(YS, WPp, p_g, p_b2, nullptr, nullptr,
                                       p_bias, x, X2, Z, nullptr);

  // mlp1: z2 = lif(bn1(z@w1^T + b1))
  gemm_i8<2><<<8192, 256, 0, stream>>>(Z, W1p, bn1g, bn1b, nullptr, nullptr,
                                       b1, nullptr, nullptr, Z2, nullptr);

  // mlp2: out = x2 + bn2(z2@w2^T + b2)
  gemm_i8<3><<<2048, 256, 0, stream>>>(Z2, W2p, bn2g, bn2b, nullptr, nullptr,
                                       b2, X2, (float*)d_out, nullptr, nullptr);
}

// Round 4
// 457.666 us; speedup vs baseline: 1.1727x; 1.1311x over previous
//
#include <hip/hip_runtime.h>

typedef unsigned int u32;
typedef unsigned char u8;
typedef unsigned short u16;
typedef __attribute__((ext_vector_type(4))) u32 u32x4;
typedef __attribute__((ext_vector_type(4))) int i32x4;
typedef __attribute__((ext_vector_type(4))) float f32x4;

#define DEV __device__ __forceinline__

// ---------------- workspace layout (bytes) ----------------
static constexpr size_t XS_OFF  = 0;                            // 16 MB
static constexpr size_t QS_OFF  = XS_OFF  + (size_t)16777216;   // 16 MB (later aliased as YS)
static constexpr size_t KS_OFF  = QS_OFF  + (size_t)16777216;   // 16 MB
static constexpr size_t ATT_OFF = KS_OFF  + (size_t)16777216;   // 1 MB (uses 512KB)
static constexpr size_t X2_OFF  = ATT_OFF + (size_t)1048576;    // 64 MB
static constexpr size_t Z2_OFF  = X2_OFF  + (size_t)67108864;   // 64 MB
static constexpr size_t WQK_OFF = Z2_OFF  + (size_t)67108864;   // 512 KB (q||k digit planes)
static constexpr size_t WP_OFF  = WQK_OFF + (size_t)524288;     // 256 KB
static constexpr size_t W1_OFF  = WP_OFF  + (size_t)262144;     // 1 MB
static constexpr size_t W2_OFF  = W1_OFF  + (size_t)1048576;    // 1 MB
static constexpr size_t WS_NEED = W2_OFF  + (size_t)1048576;
// aliases: YS = QS (QS dead after attn_k), Z = XS (XS dead after gemm<0>)

// ---------------- global_load_lds helper (width 16, linear dest) ----------------
DEV void gl_lds16(const void* gsrc, void* ldst){
  __builtin_amdgcn_global_load_lds(
      (const __attribute__((address_space(1))) unsigned int*)gsrc,
      (__attribute__((address_space(3))) unsigned int*)ldst, 16, 0, 0);
}

// ---------------- merged weight prep: f32 -> 4 signed-i8 digit planes, frag order ----
// w = Mhi*2^-15 + Mlo*2^-31 (|err| <= 0.5*2^-31); Mhi = d0*256+d1, Mlo = d2*256+d3
// frag (g,kt,ot): lane l, byte j  <->  w[o = ot*16+(l&15)][k = kt*64+(l>>4)*16+j]
__global__ __launch_bounds__(256) void prep_all(
    const float* __restrict__ q_w, const float* __restrict__ k_w,
    const float* __restrict__ p_w, const float* __restrict__ w1,
    const float* __restrict__ w2,
    signed char* __restrict__ WQK, signed char* __restrict__ WP,
    signed char* __restrict__ W1p, signed char* __restrict__ W2p)
{
  const int bb = blockIdx.x;
  const float* S; signed char* D; int O, Ck, OTs, otbase, base;
  if      (bb < 16) { S=q_w; D=WQK; O=256;  Ck=256;  OTs=32; otbase=0;  base=0;   }
  else if (bb < 32) { S=k_w; D=WQK; O=256;  Ck=256;  OTs=32; otbase=16; base=16;  }
  else if (bb < 48) { S=p_w; D=WP;  O=256;  Ck=256;  OTs=16; otbase=0;  base=32;  }
  else if (bb <112) { S=w1;  D=W1p; O=1024; Ck=256;  OTs=64; otbase=0;  base=48;  }
  else              { S=w2;  D=W2p; O=256;  Ck=1024; OTs=16; otbase=0;  base=112; }
  int tid = (bb - base)*256 + threadIdx.x;
  int lane = tid & 63; int fo = tid >> 6;
  int OT = O >> 4; int KT = Ck >> 6;
  int kt = fo / OT; int ot = fo - kt*OT;
  int o = (ot<<4) + (lane&15);
  int c = (kt<<6) + ((lane>>4)<<4);
  const float* sp = S + (size_t)o*Ck + c;
  u8 dg[4][16];
#pragma unroll
  for (int j=0;j<16;j++){
    double w = (double)sp[j];
    int Mhi = (int)__double2ll_rn(w * 32768.0);
    double r = w - (double)Mhi * (1.0/32768.0);
    int Mlo = (int)__double2ll_rn(r * 2147483648.0);
    if (Mlo > 32639){ Mhi += 1; Mlo -= 65536; }
    int d1 = (int)(signed char)(Mhi & 255); int d0 = (Mhi - d1) >> 8;
    int d3 = (int)(signed char)(Mlo & 255); int d2 = (Mlo - d3) >> 8;
    dg[0][j]=(u8)d0; dg[1][j]=(u8)d1; dg[2][j]=(u8)d2; dg[3][j]=(u8)d3;
  }
#pragma unroll
  for (int g=0; g<4; g++){
    signed char* dp = D + ((size_t)((g*KT + kt)*OTs + otbase + ot)<<10) + lane*16;
    *(u32x4*)dp = *(const u32x4*)dg[g];
  }
}

// ---------------- LIF on x -> xs spikes u8 [t][b][n][256] (exact f32 mirror) --------
__global__ __launch_bounds__(256,4) void lif_x(const float* __restrict__ X, u8* __restrict__ XSo)
{
  int tid = blockIdx.x*256 + threadIdx.x;          // 524288
  int n = tid & 1023; int oct = (tid>>10)&31; int b = tid>>15;
  int c0 = oct<<3;
  float mem[8];
#pragma unroll
  for (int i=0;i<8;i++) mem[i]=0.f;
#pragma unroll
  for (int t=0;t<4;t++){
    unsigned long long pk = 0ull;
    const float* xp = X + ((size_t)(((t*16+b)<<8) + c0)<<10) + n;
#pragma unroll
    for (int i=0;i<8;i++){
      float xv = xp[(size_t)i<<10];
      mem[i] = __fadd_rn(__fmul_rn(mem[i],0.5f), xv);
      bool s = mem[i] >= 1.0f;
      if (s) pk |= (1ull << (i*8));
      mem[i] = s? 0.f : mem[i];
    }
    *(unsigned long long*)(XSo + ((size_t)(((t*16+b)<<10) + n)<<8) + c0) = pk;
  }
}

// ---------------- attention: exact per-d EMA via history tables + LIF(0.5) ----------
DEV u32 nib4(u32 u){ return ((u & 0x01010101u) * 0x01020408u) >> 24; }
DEV u32 pk16(u32x4 v){ return nib4(v[0]) | (nib4(v[1])<<4) | (nib4(v[2])<<8) | (nib4(v[3])<<12); }

__global__ __launch_bounds__(256,4) void attn_k(const u8* __restrict__ QS, u8* __restrict__ ATT,
                                                const float* __restrict__ alpha_p)
{
  const int tid = threadIdx.x; const int l = tid & 63; const int wv = tid>>6;
  int wid = blockIdx.x*4 + wv;                 // 0..2047
  int b = wid >> 7; int nc = wid & 127; int n0 = nc<<3;
  int nr = (l>>3)&7; int ch8 = l&7;
  const float a = alpha_p[0]; const float oma = __fsub_rn(1.0f, a);
  u32 mk[4];
#pragma unroll
  for (int t=0;t<4;t++){
    const u32x4* p = (const u32x4*)(QS + ((size_t)(((t*16+b)<<10) + n0 + nr) << 8));
    u32x4 v0 = p[ch8]; u32x4 v1 = p[8+ch8];
    u32 pa = pk16(v0), pb = pk16(v1);
    u32 qa = __shfl_xor(pa, 1); u32 qb = __shfl_xor(pb, 1);
    mk[t] = (l&1)? (qb | (pb<<16)) : (pa | (qa<<16));
  }
  float mt1[2], mt2[4], mt3[8];
#pragma unroll
  for (int q0=0;q0<2;q0++){
    mt1[q0] = __fadd_rn(__fmul_rn(a,(float)q0), __fmul_rn(oma,(float)q0));
#pragma unroll
    for (int q1=0;q1<2;q1++){
      mt2[q0+(q1<<1)] = __fadd_rn(__fmul_rn(a,mt1[q0]), __fmul_rn(oma,(float)q1));
#pragma unroll
      for (int q2=0;q2<2;q2++)
        mt3[q0+(q1<<1)+(q2<<2)] = __fadd_rn(__fmul_rn(a,mt2[q0+(q1<<1)]), __fmul_rn(oma,(float)q2));
    }
  }
  const int h = ((l&7)>>1) + ((l&1)<<2);
  const int n = n0 + nr;
  float mem = 0.f;
#pragma unroll
  for (int t=0;t<4;t++){
    u32 act = mk[0];
    if (t>=1) act |= mk[1];
    if (t>=2) act |= mk[2];
    if (t>=3) act |= mk[3];
    float qsum = 0.f;
    while (act){
      int d = __builtin_ctz(act); act &= act-1;
      int b0 = (mk[0]>>d)&1;
      float m;
      if (t==0) m = (float)b0;
      else if (t==1) m = mt1[b0];
      else if (t==2) m = mt2[b0 + (((mk[1]>>d)&1)<<1)];
      else m = mt3[b0 + (((mk[1]>>d)&1)<<1) + (((mk[2]>>d)&1)<<2)];
      float qd = (float)((mk[t]>>d)&1);
      qsum = __fadd_rn(qsum, __fadd_rn(m, qd));   // ascending d; zero terms exact no-ops
    }
    mem = __fadd_rn(__fmul_rn(mem, 0.5f), qsum);
    bool s = mem >= 0.5f;
    ATT[((size_t)(((t*16+b)<<3) + h)<<10) + n] = s? (u8)1 : (u8)0;
    mem = s? 0.f : mem;
  }
}

// ---------------- y = k-spikes AND attn (exact {0,1}) ----------------
__global__ __launch_bounds__(256) void mask_k(const u8* __restrict__ KS,
                                              const u8* __restrict__ ATT, u8* __restrict__ YS)
{
  int tid = blockIdx.x*256 + threadIdx.x;        // 1048576
  int c4 = tid & 15; int n = (tid>>4) & 1023; int tb = tid >> 14;
  int h = c4 >> 1;
  u8 m = ATT[((size_t)((tb<<3) + h)<<10) + n];
  size_t row = ((size_t)((tb<<10)+n))<<8;
  u32x4 v = *(const u32x4*)(KS + row + c4*16);
  if (!m) v = (u32x4){0,0,0,0};
  *(u32x4*)(YS + row + c4*16) = v;
}

// ---------------- exact spike GEMM via 4-digit i8 MFMA ----------------
// out[n][o] = sum_c spike[n][c] * w[o][c]  (exact integer digit sums, double-combined)
// block: n64 x o32 x t4. A: direct global->register fragments (compiler-scheduled,
// no barriers). B: LDS, staged in 32KB super-steps (1 barrier pair per super-step).
template<int MODE>
__global__ __launch_bounds__(256,2) void gemm_i8(
    const u8* __restrict__ A, const signed char* __restrict__ W,
    const float* __restrict__ G1, const float* __restrict__ B1,
    const float* __restrict__ G2, const float* __restrict__ B2,
    const float* __restrict__ BIAS, const float* __restrict__ XRES,
    float* __restrict__ FOUT, u8* __restrict__ SOUT, u8* __restrict__ SOUT2)
{
  constexpr int KC   = (MODE==3)? 1024 : 256;
  constexpr int KTF  = KC >> 6;                   // 4 or 16
  constexpr int NSUP = KTF >> 2;                  // 1 or 4 super-steps
  constexpr int OTOT = (MODE==0)? 32 : (MODE==2)? 64 : 16;
  constexpr int NOB  = OTOT >> 1;
  constexpr int NWG  = NOB*256;

  const int tid = threadIdx.x;
  const int bid = blockIdx.x;
  const int wid = (bid & 7)*(NWG>>3) + (bid>>3);  // bijective XCD swizzle (NWG%8==0)
  const int ob = wid % NOB; const int rr = wid / NOB;
  const int nb = rr & 15; const int b = rr >> 4;

  __shared__ __align__(16) u8 Bl[32768];          // 32 frags x 1KB: [g4][os2][ktl4]

  const int lane = tid & 63, wv = tid >> 6;

  // per-t A fragment base: lane l -> row (lane&15), k-chunk (lane>>4)*16
  const u8* aB[4];
#pragma unroll
  for (int t=0;t<4;t++)
    aB[t] = A + (size_t)(((t*16 + b)<<10) + nb*64 + (wv<<4) + (lane&15))*KC + ((lane>>4)<<4);

  i32x4 acc[4][2][4];                             // [digit g][os][t]
#pragma unroll
  for (int g=0;g<4;g++)
#pragma unroll
    for (int os=0;os<2;os++)
#pragma unroll
      for (int t=0;t<4;t++) acc[g][os][t] = (i32x4){0,0,0,0};

#pragma unroll
  for (int s=0; s<NSUP; ++s){
    if (s) __syncthreads();                       // prior LDS reads done before overwrite
    // stage 32KB of B: wave wv stages frags f = wv*8..wv*8+7
#pragma unroll
    for (int j=0;j<8;j++){
      const int f = (wv<<3) + j;                  // f = (g*2+os)*4 + ktl
      const int g = f>>3, os = (f>>2)&1, ktl = f&3;
      const signed char* bs = W + ((size_t)((g*KTF + (s<<2)+ktl)*OTOT + ob*2 + os)<<10) + (lane<<4);
      gl_lds16(bs, Bl + (f<<10));
    }
    asm volatile("s_waitcnt vmcnt(0)" ::: "memory");
    __builtin_amdgcn_s_barrier();                 // B visible to all waves

#pragma unroll
    for (int ktl=0; ktl<4; ++ktl){
      const int kt = (s<<2) + ktl;
      i32x4 af[4];
#pragma unroll
      for (int t=0;t<4;t++)
        af[t] = *(const i32x4*)(aB[t] + kt*64);   // direct global A frag (vmcnt-tracked)
      __builtin_amdgcn_s_setprio(1);
#pragma unroll
      for (int g=0; g<4; ++g)
#pragma unroll
        for (int os=0; os<2; ++os){
          i32x4 bf = *(const i32x4*)(Bl + (((((g<<1)+os)<<2) | ktl)<<10) + (lane<<4));
#pragma unroll
          for (int t=0;t<4;t++)
            acc[g][os][t] = __builtin_amdgcn_mfma_i32_16x16x64_i8(af[t], bf, acc[g][os][t], 0,0,0);
        }
      __builtin_amdgcn_s_setprio(0);
    }
  }

  // ---------------- digit combine (exact) + bn + LIF epilogues ----------------
  const int g4 = lane >> 4;
  const int nq = nb*64 + (wv<<4) + (g4<<2);

  float pre[2][4][4];                             // [os][t][jj]
#pragma unroll
  for (int os=0;os<2;++os)
#pragma unroll
    for (int t=0;t<4;++t)
#pragma unroll
      for (int jj=0;jj<4;++jj){
        int shi = (acc[0][os][t][jj] << 8) + acc[1][os][t][jj];
        int slo = (acc[2][os][t][jj] << 8) + acc[3][os][t][jj];
        pre[os][t][jj] = (float)((double)shi * 0x1p-15 + (double)slo * 0x1p-31);
      }

  if constexpr (MODE==0){
#pragma unroll
    for (int os=0; os<2; ++os){
      const int o = (ob<<5) + (os<<4) + (lane&15);   // 0..511 over q||k
      const int matk = o>>8; const int om = o & 255;
      const float gg = (matk? G2 : G1)[om];
      const float bb = (matk? B2 : B1)[om];
      u8* sp = matk? SOUT2 : SOUT;
#pragma unroll
      for (int jj=0;jj<4;jj++){
        float mem = 0.f; const int n = nq + jj;
#pragma unroll
        for (int t=0;t<4;t++){
          float v = __fadd_rn(__fmul_rn(pre[os][t][jj], gg), bb);
          mem = __fadd_rn(__fmul_rn(mem, 0.5f), v);
          const bool s = mem >= 1.0f;
          sp[(size_t)(((t*16 + b)<<10) + n)*256 + om] = s? (u8)1 : (u8)0;
          mem = s? 0.f : mem;
        }
      }
    }
  } else if constexpr (MODE==1){
#pragma unroll
    for (int os=0; os<2; ++os){
      const int o = (ob<<5) + (os<<4) + (lane&15);   // 0..255
      const float pg = G1[o], pb2v = B1[o], pbv = BIAS[o];
      float xv[4][4];
#pragma unroll
      for (int t=0;t<4;t++){
        const size_t base = ((size_t)(((t*16 + b)<<8) + o)<<10) + nq;
        const f32x4 xq = *(const f32x4*)(XRES + base);
        f32x4 ov;
#pragma unroll
        for (int jj=0;jj<4;jj++){
          float y2 = __fadd_rn(__fmul_rn(__fadd_rn(pre[os][t][jj], pbv), pg), pb2v);
          float xx = __fadd_rn(xq[jj], y2);
          xv[t][jj] = xx; ov[jj] = xx;
        }
        *(f32x4*)(FOUT + base) = ov;                 // x2 = x + y
      }
#pragma unroll
      for (int jj=0;jj<4;jj++){
        float mem = 0.f; const int n = nq + jj;
#pragma unroll
        for (int t=0;t<4;t++){
          mem = __fadd_rn(__fmul_rn(mem, 0.5f), xv[t][jj]);
          const bool s = mem >= 1.0f;
          SOUT[(size_t)(((t*16 + b)<<10) + n)*256 + o] = s? (u8)1 : (u8)0;   // z spikes
          mem = s? 0.f : mem;
        }
      }
    }
  } else if constexpr (MODE==2){
#pragma unroll
    for (int os=0; os<2; ++os){
      const int o = (ob<<5) + (os<<4) + (lane&15);   // 0..1023
      const float gg = G1[o], bb = B1[o], bv = BIAS[o];
#pragma unroll
      for (int jj=0;jj<4;jj++){
        float mem = 0.f; const int n = nq + jj;
#pragma unroll
        for (int t=0;t<4;t++){
          float v = __fadd_rn(__fmul_rn(__fadd_rn(pre[os][t][jj], bv), gg), bb);
          mem = __fadd_rn(__fmul_rn(mem, 0.5f), v);
          const bool s = mem >= 1.0f;
          SOUT[(size_t)(((t*16 + b)<<10) + n)*1024 + o] = s? (u8)1 : (u8)0;  // z2 spikes
          mem = s? 0.f : mem;
        }
      }
    }
  } else {
#pragma unroll
    for (int os=0; os<2; ++os){
      const int o = (ob<<5) + (os<<4) + (lane&15);   // 0..255
      const float gg = G1[o], bb = B1[o], bv = BIAS[o];
#pragma unroll
      for (int t=0;t<4;t++){
        const size_t base = ((size_t)(((t*16 + b)<<8) + o)<<10) + nq;
        const f32x4 xq = *(const f32x4*)(XRES + base);
        f32x4 ov;
#pragma unroll
        for (int jj=0;jj<4;jj++){
          float v = __fadd_rn(__fmul_rn(__fadd_rn(pre[os][t][jj], bv), gg), bb);
          ov[jj] = __fadd_rn(xq[jj], v);
        }
        *(f32x4*)(FOUT + base) = ov;                 // final output
      }
    }
  }
}

// ---------------- host launcher ----------------
extern "C" void kernel_launch(void* const* d_in, const int* in_sizes, int n_in,
                              void* d_out, int out_size, void* d_ws, size_t ws_size,
                              hipStream_t stream)
{
  (void)in_sizes; (void)n_in; (void)out_size;
  if (ws_size < WS_NEED) return;

  const float* x      = (const float*)d_in[0];
  const float* q_w    = (const float*)d_in[1];
  const float* q_g    = (const float*)d_in[2];
  const float* q_b    = (const float*)d_in[3];
  const float* k_w    = (const float*)d_in[4];
  const float* k_g    = (const float*)d_in[5];
  const float* k_b    = (const float*)d_in[6];
  const float* p_w    = (const float*)d_in[7];
  const float* p_bias = (const float*)d_in[8];
  const float* p_g    = (const float*)d_in[9];
  const float* p_b2   = (const float*)d_in[10];
  const float* alpha  = (const float*)d_in[11];
  const float* w1     = (const float*)d_in[12];
  const float* b1     = (const float*)d_in[13];
  const float* bn1g   = (const float*)d_in[14];
  const float* bn1b   = (const float*)d_in[15];
  const float* w2     = (const float*)d_in[16];
  const float* b2     = (const float*)d_in[17];
  const float* bn2g   = (const float*)d_in[18];
  const float* bn2b   = (const float*)d_in[19];

  u8* ws  = (u8*)d_ws;
  u8* XS  = ws + XS_OFF;
  u8* QS  = ws + QS_OFF;
  u8* KS  = ws + KS_OFF;
  u8* ATT = ws + ATT_OFF;
  float* X2 = (float*)(ws + X2_OFF);
  u8* Z2  = ws + Z2_OFF;
  u8* YS  = QS;                        // alias: QS dead after attn_k
  u8* Z   = XS;                        // alias: XS dead after gemm<0>
  signed char* WQK = (signed char*)(ws + WQK_OFF);
  signed char* WPp = (signed char*)(ws + WP_OFF);
  signed char* W1p = (signed char*)(ws + W1_OFF);
  signed char* W2p = (signed char*)(ws + W2_OFF);

  prep_all<<<176, 256, 0, stream>>>(q_w, k_w, p_w, w1, w2, WQK, WPp, W1p, W2p);

  lif_x<<<2048, 256, 0, stream>>>(x, XS);

  // QK fused (o-space = q||k, 512): q,k spikes
  gemm_i8<0><<<4096, 256, 0, stream>>>(XS, WQK, q_g, q_b, k_g, k_b,
                                       nullptr, nullptr, nullptr, QS, KS);

  attn_k<<<512, 256, 0, stream>>>(QS, ATT, alpha);
  mask_k<<<4096, 256, 0, stream>>>(KS, ATT, YS);

  // proj: x2 = x + bn(y@proj_w + bias), z = lif(x2)
  gemm_i8<1><<<2048, 256, 0, stream>>>(YS, WPp, p_g, p_b2, nullptr, nullptr,
                                       p_bias, x, X2, Z, nullptr);

  // mlp1: z2 = lif(bn1(z@w1^T + b1))
  gemm_i8<2><<<8192, 256, 0, stream>>>(Z, W1p, bn1g, bn1b, nullptr, nullptr,
                                       b1, nullptr, nullptr, Z2, nullptr);

  // mlp2: out = x2 + bn2(z2@w2^T + b2)
  gemm_i8<3><<<2048, 256, 0, stream>>>(Z2, W2p, bn2g, bn2b, nullptr, nullptr,
                                       b2, X2, (float*)d_out, nullptr, nullptr);
}